// Round 10
// baseline (2471.894 us; speedup 1.0000x reference)
//
#include <hip/hip_runtime.h>
#include <hip/hip_fp16.h>
#include <cstdint>

#define CAP 32
#define WAVES 4

typedef __half half_t;

__device__ __forceinline__ float4 cvt4(uint2 u) {
  __half2 h0 = *reinterpret_cast<const __half2*>(&u.x);
  __half2 h1 = *reinterpret_cast<const __half2*>(&u.y);
  float2 f0 = __half22float2(h0);
  float2 f1 = __half22float2(h1);
  return make_float4(f0.x, f0.y, f1.x, f1.y);
}

__device__ __forceinline__ float4 ldh4(const half_t* p) {
  return cvt4(*reinterpret_cast<const uint2*>(p));
}

__device__ __forceinline__ void sth4(half_t* p, float x, float y, float z, float w) {
  __half2 h0 = __floats2half2_rn(x, y);
  __half2 h1 = __floats2half2_rn(z, w);
  uint2 u;
  u.x = *reinterpret_cast<unsigned int*>(&h0);
  u.y = *reinterpret_cast<unsigned int*>(&h1);
  *reinterpret_cast<uint2*>(p) = u;
}

// ---------------------------------------------------------------- transpose
__global__ __launch_bounds__(256) void transpose_kernel(
    const float* __restrict__ in, half_t* __restrict__ out, int V) {
  __shared__ float t[32][33];
  const int f0 = blockIdx.y * 32;
  const int v0 = blockIdx.x * 32;
  const int tid = threadIdx.x;
  const int fi = tid >> 5;
  const int vi = tid & 31;
#pragma unroll
  for (int k = 0; k < 4; ++k) {
    int f = fi + 8 * k;
    t[f][vi] = in[(size_t)(f0 + f) * V + (v0 + vi)];
  }
  __syncthreads();
  const int vl = tid >> 5;
  const int fl = tid & 31;
#pragma unroll
  for (int k = 0; k < 4; ++k) {
    int v = vl + 8 * k;
    out[(size_t)(v0 + v) * 256 + (f0 + fl)] = __float2half_rn(t[fl][v]);
  }
}

// ---------------------------------------------------------------- edge table
__global__ __launch_bounds__(256) void init_slots(int2* __restrict__ slots, int total) {
  int i = blockIdx.x * 256 + threadIdx.x;
  if (i < total) slots[i] = make_int2(i >> 5, 0);  // self edge, weight 0
}

__global__ __launch_bounds__(256) void fill_kernel(
    const int* __restrict__ src, const int* __restrict__ dst,
    const float* __restrict__ w, int* __restrict__ cursor,
    int2* __restrict__ slots, int E) {
  int e = blockIdx.x * 256 + threadIdx.x;
  if (e >= E) return;
  int d = dst[e];
  int pos = atomicAdd(&cursor[d], 1);
  if (pos < CAP) slots[(size_t)d * CAP + pos] = make_int2(src[e], __float_as_int(w[e]));
}

__global__ void ident_affine(float* aff) {
  int c = threadIdx.x;
  if (c < 16) { aff[c] = 1.f; aff[16 + c] = 0.f; }
}

// ---------------------------------------------------------------- cheb pass
// Affine fold: layer input y = A∘x + B (deferred BN), applied on the fly.
// PASS 1: X1 = lap(y(G)); O = bias + y(G)@W0 + X1@W1; D = X1
// PASS 2: X2 = 2*lap(G) − y(Pv); O += X2@W2; D = X2
// PASS 3: X3 = 2*lap(G) − Pv;  O += X3@W3; epilogue
// EPI: 0 none, 1 relu+stats, 2 res+relu+stats, 3 res+relu
// Gather: wave-uniform branch — deg<=8 nodes use one 8-deep burst; deg>8
// nodes use 16-deep bursts (uint2 staging, 32 VGPR peak). Own-row / prev-row
// / affine loads deferred to after the loop to cap loop-live VGPR (~45).
template <int PASS, int EPI>
__global__ __launch_bounds__(256, 8) void cheb_pass(
    const half_t* __restrict__ G, const half_t* __restrict__ Pv,
    half_t* __restrict__ D, half_t* __restrict__ O,
    const half_t* __restrict__ resid,
    const int2* __restrict__ slots, const int* __restrict__ cnt,
    const float* __restrict__ Wl, const float* __restrict__ bl,
    const float* __restrict__ aff, float* __restrict__ statsBuf, int V) {
  __shared__ float xl[WAVES][272];   // 16*17 per wave, conflict-free
  __shared__ float wl[512];
  const int tid = threadIdx.x;
  if (PASS == 1) {
    wl[tid] = Wl[tid];
    wl[256 + tid] = Wl[256 + tid];
  } else if (PASS == 2) {
    wl[tid] = Wl[512 + tid];
  } else {
    wl[tid] = Wl[768 + tid];
  }
  __syncthreads();
  const int wave = tid >> 6, lane = tid & 63;
  const int v = blockIdx.x * WAVES + wave;
  if (v >= V) return;
  const int f0 = lane << 2;
  const int c0 = f0 & 15;
  const size_t rowoff = (((size_t)v) << 8) + f0;

  int2 myslot = slots[((size_t)v << 5) + (lane & 31)];   // lane l holds edge l
  int n = cnt[v];
  n = n > CAP ? CAP : n;

  float4 acc = make_float4(0.f, 0.f, 0.f, 0.f);
  float sw = 0.f;
  if (n > 8) {
    // 16-deep bursts (padded slots are (self, w=0): cache-hot, safe)
    int n16 = (n + 15) & ~15;
    for (int base = 0; base < n16; base += 16) {
      uint2 raw[16];
#pragma unroll
      for (int j = 0; j < 16; ++j) {
        int s = __shfl(myslot.x, base + j);
        raw[j] = *reinterpret_cast<const uint2*>(G + (((size_t)s) << 8) + f0);
      }
#pragma unroll
      for (int j = 0; j < 16; ++j) {
        float wj = __int_as_float(__shfl(myslot.y, base + j));
        float4 a = cvt4(raw[j]);
        acc.x = fmaf(wj, a.x, acc.x);
        acc.y = fmaf(wj, a.y, acc.y);
        acc.z = fmaf(wj, a.z, acc.z);
        acc.w = fmaf(wj, a.w, acc.w);
        if (PASS == 1) sw += wj;
      }
    }
  } else {
    // single 8-deep burst covers deg<=8 (~55% of nodes; deg=0 safe via pads)
    uint2 raw[8];
#pragma unroll
    for (int j = 0; j < 8; ++j) {
      int s = __shfl(myslot.x, j);
      raw[j] = *reinterpret_cast<const uint2*>(G + (((size_t)s) << 8) + f0);
    }
#pragma unroll
    for (int j = 0; j < 8; ++j) {
      float wj = __int_as_float(__shfl(myslot.y, j));
      float4 a = cvt4(raw[j]);
      acc.x = fmaf(wj, a.x, acc.x);
      acc.y = fmaf(wj, a.y, acc.y);
      acc.z = fmaf(wj, a.z, acc.z);
      acc.w = fmaf(wj, a.w, acc.w);
      if (PASS == 1) sw += wj;
    }
  }

  // deferred own-row / prev-row / affine loads (L2-hot streams)
  float4 g = ldh4(G + rowoff);
  float4 p = make_float4(0.f, 0.f, 0.f, 0.f);
  if (PASS != 1) p = ldh4(Pv + rowoff);
  float4 A4 = *reinterpret_cast<const float4*>(aff + c0);
  float4 B4 = *reinterpret_cast<const float4*>(aff + 16 + c0);

  // recursion combine (+ folded BN affine)
  float4 xn, gy;
  if (PASS == 1) {
    gy.x = fmaf(A4.x, g.x, B4.x); gy.y = fmaf(A4.y, g.y, B4.y);
    gy.z = fmaf(A4.z, g.z, B4.z); gy.w = fmaf(A4.w, g.w, B4.w);
    float swm1 = sw - 1.f;
    xn.x = A4.x * (acc.x - g.x) + B4.x * swm1;
    xn.y = A4.y * (acc.y - g.y) + B4.y * swm1;
    xn.z = A4.z * (acc.z - g.z) + B4.z * swm1;
    xn.w = A4.w * (acc.w - g.w) + B4.w * swm1;
  } else if (PASS == 2) {
    xn.x = 2.f * (acc.x - g.x) - fmaf(A4.x, p.x, B4.x);
    xn.y = 2.f * (acc.y - g.y) - fmaf(A4.y, p.y, B4.y);
    xn.z = 2.f * (acc.z - g.z) - fmaf(A4.z, p.z, B4.z);
    xn.w = 2.f * (acc.w - g.w) - fmaf(A4.w, p.w, B4.w);
  } else {
    xn.x = 2.f * (acc.x - g.x) - p.x;
    xn.y = 2.f * (acc.y - g.y) - p.y;
    xn.z = 2.f * (acc.z - g.z) - p.z;
    xn.w = 2.f * (acc.w - g.w) - p.w;
  }
  if (PASS != 3) {
    sth4(D + rowoff, xn.x, xn.y, xn.z, xn.w);
  }

  // ---- epilogue: out accumulation via per-wave LDS row + 16x16 matmul ----
  const int b = lane >> 2;
  const int oc = (lane & 3) << 2;
  float* xw = xl[wave];
  const int sbase = f0 + b;  // padded slot: f + f/16
  float o[4];
  if (PASS == 1) {
    o[0] = bl[oc + 0]; o[1] = bl[oc + 1]; o[2] = bl[oc + 2]; o[3] = bl[oc + 3];
    xw[sbase + 0] = gy.x; xw[sbase + 1] = gy.y;
    xw[sbase + 2] = gy.z; xw[sbase + 3] = gy.w;
    __builtin_amdgcn_wave_barrier();
    const float* xb = xw + b * 17;
#pragma unroll
    for (int i = 0; i < 16; ++i) {
      float xi = xb[i];
      o[0] = fmaf(xi, wl[i * 16 + oc + 0], o[0]);
      o[1] = fmaf(xi, wl[i * 16 + oc + 1], o[1]);
      o[2] = fmaf(xi, wl[i * 16 + oc + 2], o[2]);
      o[3] = fmaf(xi, wl[i * 16 + oc + 3], o[3]);
    }
    __builtin_amdgcn_wave_barrier();
  } else {
    o[0] = o[1] = o[2] = o[3] = 0.f;
  }
  xw[sbase + 0] = xn.x; xw[sbase + 1] = xn.y;
  xw[sbase + 2] = xn.z; xw[sbase + 3] = xn.w;
  __builtin_amdgcn_wave_barrier();
  {
    const float* xb = xw + b * 17;
    const float* wm = (PASS == 1) ? (wl + 256) : wl;
#pragma unroll
    for (int i = 0; i < 16; ++i) {
      float xi = xb[i];
      o[0] = fmaf(xi, wm[i * 16 + oc + 0], o[0]);
      o[1] = fmaf(xi, wm[i * 16 + oc + 1], o[1]);
      o[2] = fmaf(xi, wm[i * 16 + oc + 2], o[2]);
      o[3] = fmaf(xi, wm[i * 16 + oc + 3], o[3]);
    }
  }
  half_t* op = O + rowoff;
  if (PASS == 1) {
    sth4(op, o[0], o[1], o[2], o[3]);
  } else if (PASS == 2) {
    float4 oprev = ldh4(op);
    sth4(op, o[0] + oprev.x, o[1] + oprev.y, o[2] + oprev.z, o[3] + oprev.w);
  } else {
    float4 oprev = ldh4(op);
    o[0] += oprev.x; o[1] += oprev.y; o[2] += oprev.z; o[3] += oprev.w;
    if (EPI >= 2) {
      float4 r = ldh4(resid + rowoff);
      o[0] += fmaf(A4.x, r.x, B4.x);
      o[1] += fmaf(A4.y, r.y, B4.y);
      o[2] += fmaf(A4.z, r.z, B4.z);
      o[3] += fmaf(A4.w, r.w, B4.w);
    }
    o[0] = fmaxf(o[0], 0.f); o[1] = fmaxf(o[1], 0.f);
    o[2] = fmaxf(o[2], 0.f); o[3] = fmaxf(o[3], 0.f);
    sth4(op, o[0], o[1], o[2], o[3]);
    if (EPI == 1 || EPI == 2) {
      float s0 = o[0], s1 = o[1], s2 = o[2], s3 = o[3];
      float q0 = o[0] * o[0], q1 = o[1] * o[1], q2 = o[2] * o[2], q3 = o[3] * o[3];
#pragma unroll
      for (int d = 4; d < 64; d <<= 1) {
        s0 += __shfl_xor(s0, d); s1 += __shfl_xor(s1, d);
        s2 += __shfl_xor(s2, d); s3 += __shfl_xor(s3, d);
        q0 += __shfl_xor(q0, d); q1 += __shfl_xor(q1, d);
        q2 += __shfl_xor(q2, d); q3 += __shfl_xor(q3, d);
      }
      if (lane < 4) {
        float* sb = statsBuf + ((blockIdx.x & 255) << 5);
        atomicAdd(&sb[(lane << 2) + 0], s0);
        atomicAdd(&sb[(lane << 2) + 1], s1);
        atomicAdd(&sb[(lane << 2) + 2], s2);
        atomicAdd(&sb[(lane << 2) + 3], s3);
        atomicAdd(&sb[16 + (lane << 2) + 0], q0);
        atomicAdd(&sb[16 + (lane << 2) + 1], q1);
        atomicAdd(&sb[16 + (lane << 2) + 2], q2);
        atomicAdd(&sb[16 + (lane << 2) + 3], q3);
      }
    }
  }
}

// ---------------------------------------------------------------- batch norm
__global__ void bn_finalize(const float* __restrict__ sb,
                            const float* __restrict__ gamma,
                            const float* __restrict__ beta,
                            float* __restrict__ affine, float invN) {
  int c = threadIdx.x;
  if (c >= 16) return;
  float s = 0.f, q = 0.f;
  for (int k = 0; k < 256; ++k) { s += sb[k * 32 + c]; q += sb[k * 32 + 16 + c]; }
  float mean = s * invN;
  float var = q * invN - mean * mean;
  float inv = rsqrtf(var + 1e-5f);
  float A = gamma[c] * inv;
  float B = beta[c] - mean * A;
  affine[c] = A;
  affine[16 + c] = B;
}

// ---------------------------------------------------------------- pooling
__global__ __launch_bounds__(256) void pool_kernel(const half_t* __restrict__ X,
                                                   float* __restrict__ part, int V) {
  int t = threadIdx.x;
  float m = -3.402823466e38f;
  for (int v = blockIdx.x; v < V; v += gridDim.x) {
    m = fmaxf(m, __half2float(X[(((size_t)v) << 8) + t]));
  }
  part[blockIdx.x * 256 + t] = m;
}

__global__ __launch_bounds__(256) void pool_finish(const float* __restrict__ part,
                                                   float* __restrict__ out) {
  int t = threadIdx.x;
  float m = -3.402823466e38f;
  for (int k = 0; k < 256; ++k) m = fmaxf(m, part[k * 256 + t]);
  __shared__ float pm[256];
  __shared__ float mx[16], sm[16];
  pm[t] = m;
  __syncthreads();
  if (t < 16) {
    float M = -3.402823466e38f;
    for (int c = 0; c < 16; ++c) M = fmaxf(M, pm[t * 16 + c]);
    float S = 0.f;
    for (int c = 0; c < 16; ++c) S += expf(pm[t * 16 + c] - M);
    mx[t] = M;
    sm[t] = S;
  }
  __syncthreads();
  out[t] = expf(pm[t] - mx[t >> 4]) / sm[t >> 4];
}

__global__ void sentinel_kernel(float* out, float val) {
  out[threadIdx.x] = val;
}

// ---------------------------------------------------------------- launcher
extern "C" void kernel_launch(void* const* d_in, const int* in_sizes, int n_in,
                              void* d_out, int out_size, void* d_ws, size_t ws_size,
                              hipStream_t stream) {
  const float* x       = (const float*)d_in[0];
  const float* edge_w  = (const float*)d_in[1];
  const float* weights = (const float*)d_in[2];
  const float* biases  = (const float*)d_in[3];
  const float* gamma   = (const float*)d_in[4];
  const float* beta    = (const float*)d_in[5];
  const int*   esrc    = (const int*)d_in[6];
  const int*   edst    = (const int*)d_in[7];

  const int V = in_sizes[0] / 256;
  const int E = in_sizes[1];
  const size_t NT = (size_t)V * 256;

  char* wsp = (char*)d_ws;
  auto carve = [&](size_t bytes) {
    char* p = wsp;
    wsp += (bytes + 255) & ~(size_t)255;
    return p;
  };
  half_t* P[4];
  for (int i = 0; i < 4; ++i) P[i] = (half_t*)carve(NT * sizeof(half_t));
  int2*  slots  = (int2*)carve((size_t)V * CAP * sizeof(int2));
  int*   cursor = (int*)carve((size_t)V * sizeof(int));
  float* stats  = (float*)carve(5 * 256 * 32 * sizeof(float));
  float* affine = (float*)carve(6 * 32 * sizeof(float));
  float* part   = (float*)carve(256 * 256 * sizeof(float));
  size_t needed = (size_t)(wsp - (char*)d_ws);
  if (needed > ws_size) {
    sentinel_kernel<<<1, 256, 0, stream>>>((float*)d_out, 100.0f + (float)(needed >> 20));
    return;
  }
  float* ident = affine + 5 * 32;

  hipMemsetAsync(cursor, 0, (size_t)V * sizeof(int), stream);
  hipMemsetAsync(stats, 0, 5 * 256 * 32 * sizeof(float), stream);

  const int totalSlots = V * CAP;
  init_slots<<<(totalSlots + 255) / 256, 256, 0, stream>>>(slots, totalSlots);
  ident_affine<<<1, 16, 0, stream>>>(ident);

  dim3 tg(V / 32, 8, 1);
  transpose_kernel<<<tg, 256, 0, stream>>>(x, P[0], V);
  fill_kernel<<<(E + 255) / 256, 256, 0, stream>>>(esrc, edst, edge_w, cursor, slots, E);

  const int nb = (V + WAVES - 1) / WAVES;
  const float invN = 1.f / (16.f * (float)V);

  half_t *C = P[0], *X = P[1], *Y = P[2], *Z = P[3];
  for (int blk = 0; blk < 3; ++blk) {
    const float* WA = weights + (size_t)(2 * blk) * 1024;
    const float* WB = weights + (size_t)(2 * blk + 1) * 1024;
    const float* bA = biases + (2 * blk) * 16;
    const float* bB = biases + (2 * blk + 1) * 16;
    float* stA  = stats + blk * 8192;
    float* afMid = affine + blk * 32;
    const float* afIn = (blk == 0) ? ident : (affine + (2 + blk) * 32);
    // --- cheb A (input affine folded; relu + in-block BN stats) ---
    cheb_pass<1, 0><<<nb, 256, 0, stream>>>(C, nullptr, X, Y, nullptr, slots, cursor, WA, bA, afIn, nullptr, V);
    cheb_pass<2, 0><<<nb, 256, 0, stream>>>(X, C, Z, Y, nullptr, slots, cursor, WA, nullptr, afIn, nullptr, V);
    cheb_pass<3, 1><<<nb, 256, 0, stream>>>(Z, X, nullptr, Y, nullptr, slots, cursor, WA, nullptr, ident, stA, V);
    bn_finalize<<<1, 16, 0, stream>>>(stA, gamma + blk * 16, beta + blk * 16, afMid, invN);
    // --- cheb B (mid affine folded; +residual(affine'd), relu; stats for inter-block BN) ---
    cheb_pass<1, 0><<<nb, 256, 0, stream>>>(Y, nullptr, X, Z, nullptr, slots, cursor, WB, bB, afMid, nullptr, V);
    cheb_pass<2, 0><<<nb, 256, 0, stream>>>(X, Y, Y, Z, nullptr, slots, cursor, WB, nullptr, afMid, nullptr, V);
    if (blk < 2) {
      float* stI = stats + (3 + blk) * 8192;
      float* afI = affine + (3 + blk) * 32;
      cheb_pass<3, 2><<<nb, 256, 0, stream>>>(Y, X, nullptr, Z, C, slots, cursor, WB, nullptr, afIn, stI, V);
      bn_finalize<<<1, 16, 0, stream>>>(stI, gamma + (3 + blk) * 16, beta + (3 + blk) * 16, afI, invN);
    } else {
      cheb_pass<3, 3><<<nb, 256, 0, stream>>>(Y, X, nullptr, Z, C, slots, cursor, WB, nullptr, afIn, nullptr, V);
    }
    // rotate buffers
    half_t* oC = C; half_t* oY = Y; half_t* oZ = Z;
    C = oZ; Y = oC; Z = oY;
  }
  pool_kernel<<<256, 256, 0, stream>>>(C, part, V);
  pool_finish<<<1, 256, 0, stream>>>(part, (float*)d_out);
}

// Round 11
// 2078.545 us; speedup vs baseline: 1.1892x; 1.1892x over previous
//
#include <hip/hip_runtime.h>
#include <hip/hip_fp16.h>
#include <cstdint>

#define CAP 32
#define WAVES 4

typedef __half half_t;

__device__ __forceinline__ float4 cvt4(uint2 u) {
  __half2 h0 = *reinterpret_cast<const __half2*>(&u.x);
  __half2 h1 = *reinterpret_cast<const __half2*>(&u.y);
  float2 f0 = __half22float2(h0);
  float2 f1 = __half22float2(h1);
  return make_float4(f0.x, f0.y, f1.x, f1.y);
}

__device__ __forceinline__ float4 ldh4(const half_t* p) {
  return cvt4(*reinterpret_cast<const uint2*>(p));
}

__device__ __forceinline__ void sth4(half_t* p, float x, float y, float z, float w) {
  __half2 h0 = __floats2half2_rn(x, y);
  __half2 h1 = __floats2half2_rn(z, w);
  uint2 u;
  u.x = *reinterpret_cast<unsigned int*>(&h0);
  u.y = *reinterpret_cast<unsigned int*>(&h1);
  *reinterpret_cast<uint2*>(p) = u;
}

// ---------------------------------------------------------------- transpose
__global__ __launch_bounds__(256) void transpose_kernel(
    const float* __restrict__ in, half_t* __restrict__ out, int V) {
  __shared__ float t[32][33];
  const int f0 = blockIdx.y * 32;
  const int v0 = blockIdx.x * 32;
  const int tid = threadIdx.x;
  const int fi = tid >> 5;
  const int vi = tid & 31;
#pragma unroll
  for (int k = 0; k < 4; ++k) {
    int f = fi + 8 * k;
    t[f][vi] = in[(size_t)(f0 + f) * V + (v0 + vi)];
  }
  __syncthreads();
  const int vl = tid >> 5;
  const int fl = tid & 31;
#pragma unroll
  for (int k = 0; k < 4; ++k) {
    int v = vl + 8 * k;
    out[(size_t)(v0 + v) * 256 + (f0 + fl)] = __float2half_rn(t[fl][v]);
  }
}

// ---------------------------------------------------------------- edge table
__global__ __launch_bounds__(256) void init_slots(int2* __restrict__ slots, int total) {
  int i = blockIdx.x * 256 + threadIdx.x;
  if (i < total) slots[i] = make_int2(i >> 5, 0);  // self edge, weight 0
}

__global__ __launch_bounds__(256) void fill_kernel(
    const int* __restrict__ src, const int* __restrict__ dst,
    const float* __restrict__ w, int* __restrict__ cursor,
    int2* __restrict__ slots, int E) {
  int e = blockIdx.x * 256 + threadIdx.x;
  if (e >= E) return;
  int d = dst[e];
  int pos = atomicAdd(&cursor[d], 1);
  if (pos < CAP) slots[(size_t)d * CAP + pos] = make_int2(src[e], __float_as_int(w[e]));
}

__global__ void ident_affine(float* aff) {
  int c = threadIdx.x;
  if (c < 16) { aff[c] = 1.f; aff[16 + c] = 0.f; }
}

// ---------------------------------------------------------------- cheb pass
// Affine fold: layer input y = A∘x + B (deferred BN), applied on the fly.
// PASS 1: X1 = lap(y(G)); O = bias + y(G)@W0 + X1@W1; D = X1
// PASS 2: X2 = 2*lap(G) − y(Pv); O += X2@W2; D = X2
// PASS 3: X3 = 2*lap(G) − Pv;  O += X3@W3; epilogue
// EPI: 0 none, 1 relu+stats, 2 res+relu+stats, 3 res+relu
template <int PASS, int EPI>
__global__ __launch_bounds__(256, 8) void cheb_pass(
    const half_t* __restrict__ G, const half_t* __restrict__ Pv,
    half_t* __restrict__ D, half_t* __restrict__ O,
    const half_t* __restrict__ resid,
    const int2* __restrict__ slots, const int* __restrict__ cnt,
    const float* __restrict__ Wl, const float* __restrict__ bl,
    const float* __restrict__ aff, float* __restrict__ statsBuf, int V) {
  __shared__ float xl[WAVES][272];   // 16*17 per wave, conflict-free
  __shared__ float wl[512];
  const int tid = threadIdx.x;
  if (PASS == 1) {
    wl[tid] = Wl[tid];
    wl[256 + tid] = Wl[256 + tid];
  } else if (PASS == 2) {
    wl[tid] = Wl[512 + tid];
  } else {
    wl[tid] = Wl[768 + tid];
  }
  __syncthreads();
  const int wave = tid >> 6, lane = tid & 63;
  const int v = blockIdx.x * WAVES + wave;
  if (v >= V) return;
  const int f0 = lane << 2;
  const int c0 = f0 & 15;
  const size_t rowoff = (((size_t)v) << 8) + f0;

  // per-channel affine of this pass's folded input
  float4 A4 = *reinterpret_cast<const float4*>(aff + c0);
  float4 B4 = *reinterpret_cast<const float4*>(aff + 16 + c0);

  // early independent loads: edge slots (cooperative), own row, prev row
  int2 myslot = slots[((size_t)v << 5) + (lane & 31)];   // lane l holds edge l
  float4 g = ldh4(G + rowoff);
  float4 p = make_float4(0.f, 0.f, 0.f, 0.f);
  if (PASS != 1) p = ldh4(Pv + rowoff);

  int n = cnt[v];
  n = n > CAP ? CAP : n;
  int n8 = (n + 7) & ~7;   // padded slots are (self, w=0): cache-hot, safe

  float4 acc = make_float4(0.f, 0.f, 0.f, 0.f);
  float sw = 0.f;
  for (int base = 0; base < n8; base += 8) {
    // RAW 8-deep gather: uint2 results keep only 16 VGPR live so all 8
    // loads stay simultaneously outstanding (the fp32 convert is deferred)
    uint2 raw[8];
#pragma unroll
    for (int j = 0; j < 8; ++j) {
      int s = __shfl(myslot.x, base + j);
      raw[j] = *reinterpret_cast<const uint2*>(G + (((size_t)s) << 8) + f0);
    }
#pragma unroll
    for (int j = 0; j < 8; ++j) {
      float wj = __int_as_float(__shfl(myslot.y, base + j));
      float4 a = cvt4(raw[j]);
      acc.x = fmaf(wj, a.x, acc.x);
      acc.y = fmaf(wj, a.y, acc.y);
      acc.z = fmaf(wj, a.z, acc.z);
      acc.w = fmaf(wj, a.w, acc.w);
      if (PASS == 1) sw += wj;
    }
  }

  // recursion combine (+ folded BN affine)
  float4 xn, gy;
  if (PASS == 1) {
    gy.x = fmaf(A4.x, g.x, B4.x); gy.y = fmaf(A4.y, g.y, B4.y);
    gy.z = fmaf(A4.z, g.z, B4.z); gy.w = fmaf(A4.w, g.w, B4.w);
    float swm1 = sw - 1.f;
    xn.x = A4.x * (acc.x - g.x) + B4.x * swm1;
    xn.y = A4.y * (acc.y - g.y) + B4.y * swm1;
    xn.z = A4.z * (acc.z - g.z) + B4.z * swm1;
    xn.w = A4.w * (acc.w - g.w) + B4.w * swm1;
  } else if (PASS == 2) {
    xn.x = 2.f * (acc.x - g.x) - fmaf(A4.x, p.x, B4.x);
    xn.y = 2.f * (acc.y - g.y) - fmaf(A4.y, p.y, B4.y);
    xn.z = 2.f * (acc.z - g.z) - fmaf(A4.z, p.z, B4.z);
    xn.w = 2.f * (acc.w - g.w) - fmaf(A4.w, p.w, B4.w);
  } else {
    xn.x = 2.f * (acc.x - g.x) - p.x;
    xn.y = 2.f * (acc.y - g.y) - p.y;
    xn.z = 2.f * (acc.z - g.z) - p.z;
    xn.w = 2.f * (acc.w - g.w) - p.w;
  }
  if (PASS != 3) {
    sth4(D + rowoff, xn.x, xn.y, xn.z, xn.w);
  }

  // ---- epilogue: out accumulation via per-wave LDS row + 16x16 matmul ----
  const int b = lane >> 2;
  const int oc = (lane & 3) << 2;
  float* xw = xl[wave];
  const int sbase = f0 + b;  // padded slot: f + f/16
  float o[4];
  if (PASS == 1) {
    o[0] = bl[oc + 0]; o[1] = bl[oc + 1]; o[2] = bl[oc + 2]; o[3] = bl[oc + 3];
    xw[sbase + 0] = gy.x; xw[sbase + 1] = gy.y;
    xw[sbase + 2] = gy.z; xw[sbase + 3] = gy.w;
    __builtin_amdgcn_wave_barrier();
    const float* xb = xw + b * 17;
#pragma unroll
    for (int i = 0; i < 16; ++i) {
      float xi = xb[i];
      o[0] = fmaf(xi, wl[i * 16 + oc + 0], o[0]);
      o[1] = fmaf(xi, wl[i * 16 + oc + 1], o[1]);
      o[2] = fmaf(xi, wl[i * 16 + oc + 2], o[2]);
      o[3] = fmaf(xi, wl[i * 16 + oc + 3], o[3]);
    }
    __builtin_amdgcn_wave_barrier();
  } else {
    o[0] = o[1] = o[2] = o[3] = 0.f;
  }
  xw[sbase + 0] = xn.x; xw[sbase + 1] = xn.y;
  xw[sbase + 2] = xn.z; xw[sbase + 3] = xn.w;
  __builtin_amdgcn_wave_barrier();
  {
    const float* xb = xw + b * 17;
    const float* wm = (PASS == 1) ? (wl + 256) : wl;
#pragma unroll
    for (int i = 0; i < 16; ++i) {
      float xi = xb[i];
      o[0] = fmaf(xi, wm[i * 16 + oc + 0], o[0]);
      o[1] = fmaf(xi, wm[i * 16 + oc + 1], o[1]);
      o[2] = fmaf(xi, wm[i * 16 + oc + 2], o[2]);
      o[3] = fmaf(xi, wm[i * 16 + oc + 3], o[3]);
    }
  }
  half_t* op = O + rowoff;
  if (PASS == 1) {
    sth4(op, o[0], o[1], o[2], o[3]);
  } else if (PASS == 2) {
    float4 oprev = ldh4(op);
    sth4(op, o[0] + oprev.x, o[1] + oprev.y, o[2] + oprev.z, o[3] + oprev.w);
  } else {
    float4 oprev = ldh4(op);
    o[0] += oprev.x; o[1] += oprev.y; o[2] += oprev.z; o[3] += oprev.w;
    if (EPI >= 2) {
      float4 r = ldh4(resid + rowoff);
      o[0] += fmaf(A4.x, r.x, B4.x);
      o[1] += fmaf(A4.y, r.y, B4.y);
      o[2] += fmaf(A4.z, r.z, B4.z);
      o[3] += fmaf(A4.w, r.w, B4.w);
    }
    o[0] = fmaxf(o[0], 0.f); o[1] = fmaxf(o[1], 0.f);
    o[2] = fmaxf(o[2], 0.f); o[3] = fmaxf(o[3], 0.f);
    sth4(op, o[0], o[1], o[2], o[3]);
    if (EPI == 1 || EPI == 2) {
      float s0 = o[0], s1 = o[1], s2 = o[2], s3 = o[3];
      float q0 = o[0] * o[0], q1 = o[1] * o[1], q2 = o[2] * o[2], q3 = o[3] * o[3];
#pragma unroll
      for (int d = 4; d < 64; d <<= 1) {
        s0 += __shfl_xor(s0, d); s1 += __shfl_xor(s1, d);
        s2 += __shfl_xor(s2, d); s3 += __shfl_xor(s3, d);
        q0 += __shfl_xor(q0, d); q1 += __shfl_xor(q1, d);
        q2 += __shfl_xor(q2, d); q3 += __shfl_xor(q3, d);
      }
      if (lane < 4) {
        float* sb = statsBuf + ((blockIdx.x & 255) << 5);
        atomicAdd(&sb[(lane << 2) + 0], s0);
        atomicAdd(&sb[(lane << 2) + 1], s1);
        atomicAdd(&sb[(lane << 2) + 2], s2);
        atomicAdd(&sb[(lane << 2) + 3], s3);
        atomicAdd(&sb[16 + (lane << 2) + 0], q0);
        atomicAdd(&sb[16 + (lane << 2) + 1], q1);
        atomicAdd(&sb[16 + (lane << 2) + 2], q2);
        atomicAdd(&sb[16 + (lane << 2) + 3], q3);
      }
    }
  }
}

// ---------------------------------------------------------------- batch norm
__global__ void bn_finalize(const float* __restrict__ sb,
                            const float* __restrict__ gamma,
                            const float* __restrict__ beta,
                            float* __restrict__ affine, float invN) {
  int c = threadIdx.x;
  if (c >= 16) return;
  float s = 0.f, q = 0.f;
  for (int k = 0; k < 256; ++k) { s += sb[k * 32 + c]; q += sb[k * 32 + 16 + c]; }
  float mean = s * invN;
  float var = q * invN - mean * mean;
  float inv = rsqrtf(var + 1e-5f);
  float A = gamma[c] * inv;
  float B = beta[c] - mean * A;
  affine[c] = A;
  affine[16 + c] = B;
}

// ---------------------------------------------------------------- pooling
__global__ __launch_bounds__(256) void pool_kernel(const half_t* __restrict__ X,
                                                   float* __restrict__ part, int V) {
  int t = threadIdx.x;
  float m = -3.402823466e38f;
  for (int v = blockIdx.x; v < V; v += gridDim.x) {
    m = fmaxf(m, __half2float(X[(((size_t)v) << 8) + t]));
  }
  part[blockIdx.x * 256 + t] = m;
}

__global__ __launch_bounds__(256) void pool_finish(const float* __restrict__ part,
                                                   float* __restrict__ out) {
  int t = threadIdx.x;
  float m = -3.402823466e38f;
  for (int k = 0; k < 256; ++k) m = fmaxf(m, part[k * 256 + t]);
  __shared__ float pm[256];
  __shared__ float mx[16], sm[16];
  pm[t] = m;
  __syncthreads();
  if (t < 16) {
    float M = -3.402823466e38f;
    for (int c = 0; c < 16; ++c) M = fmaxf(M, pm[t * 16 + c]);
    float S = 0.f;
    for (int c = 0; c < 16; ++c) S += expf(pm[t * 16 + c] - M);
    mx[t] = M;
    sm[t] = S;
  }
  __syncthreads();
  out[t] = expf(pm[t] - mx[t >> 4]) / sm[t >> 4];
}

__global__ void sentinel_kernel(float* out, float val) {
  out[threadIdx.x] = val;
}

// ---------------------------------------------------------------- launcher
extern "C" void kernel_launch(void* const* d_in, const int* in_sizes, int n_in,
                              void* d_out, int out_size, void* d_ws, size_t ws_size,
                              hipStream_t stream) {
  const float* x       = (const float*)d_in[0];
  const float* edge_w  = (const float*)d_in[1];
  const float* weights = (const float*)d_in[2];
  const float* biases  = (const float*)d_in[3];
  const float* gamma   = (const float*)d_in[4];
  const float* beta    = (const float*)d_in[5];
  const int*   esrc    = (const int*)d_in[6];
  const int*   edst    = (const int*)d_in[7];

  const int V = in_sizes[0] / 256;
  const int E = in_sizes[1];
  const size_t NT = (size_t)V * 256;

  char* wsp = (char*)d_ws;
  auto carve = [&](size_t bytes) {
    char* p = wsp;
    wsp += (bytes + 255) & ~(size_t)255;
    return p;
  };
  half_t* P[4];
  for (int i = 0; i < 4; ++i) P[i] = (half_t*)carve(NT * sizeof(half_t));
  int2*  slots  = (int2*)carve((size_t)V * CAP * sizeof(int2));
  int*   cursor = (int*)carve((size_t)V * sizeof(int));
  float* stats  = (float*)carve(5 * 256 * 32 * sizeof(float));
  float* affine = (float*)carve(6 * 32 * sizeof(float));
  float* part   = (float*)carve(256 * 256 * sizeof(float));
  size_t needed = (size_t)(wsp - (char*)d_ws);
  if (needed > ws_size) {
    sentinel_kernel<<<1, 256, 0, stream>>>((float*)d_out, 100.0f + (float)(needed >> 20));
    return;
  }
  float* ident = affine + 5 * 32;

  hipMemsetAsync(cursor, 0, (size_t)V * sizeof(int), stream);
  hipMemsetAsync(stats, 0, 5 * 256 * 32 * sizeof(float), stream);

  const int totalSlots = V * CAP;
  init_slots<<<(totalSlots + 255) / 256, 256, 0, stream>>>(slots, totalSlots);
  ident_affine<<<1, 16, 0, stream>>>(ident);

  dim3 tg(V / 32, 8, 1);
  transpose_kernel<<<tg, 256, 0, stream>>>(x, P[0], V);
  fill_kernel<<<(E + 255) / 256, 256, 0, stream>>>(esrc, edst, edge_w, cursor, slots, E);

  const int nb = (V + WAVES - 1) / WAVES;
  const float invN = 1.f / (16.f * (float)V);

  half_t *C = P[0], *X = P[1], *Y = P[2], *Z = P[3];
  for (int blk = 0; blk < 3; ++blk) {
    const float* WA = weights + (size_t)(2 * blk) * 1024;
    const float* WB = weights + (size_t)(2 * blk + 1) * 1024;
    const float* bA = biases + (2 * blk) * 16;
    const float* bB = biases + (2 * blk + 1) * 16;
    float* stA  = stats + blk * 8192;
    float* afMid = affine + blk * 32;
    const float* afIn = (blk == 0) ? ident : (affine + (2 + blk) * 32);
    // --- cheb A (input affine folded; relu + in-block BN stats) ---
    cheb_pass<1, 0><<<nb, 256, 0, stream>>>(C, nullptr, X, Y, nullptr, slots, cursor, WA, bA, afIn, nullptr, V);
    cheb_pass<2, 0><<<nb, 256, 0, stream>>>(X, C, Z, Y, nullptr, slots, cursor, WA, nullptr, afIn, nullptr, V);
    cheb_pass<3, 1><<<nb, 256, 0, stream>>>(Z, X, nullptr, Y, nullptr, slots, cursor, WA, nullptr, ident, stA, V);
    bn_finalize<<<1, 16, 0, stream>>>(stA, gamma + blk * 16, beta + blk * 16, afMid, invN);
    // --- cheb B (mid affine folded; +residual(affine'd), relu; stats for inter-block BN) ---
    cheb_pass<1, 0><<<nb, 256, 0, stream>>>(Y, nullptr, X, Z, nullptr, slots, cursor, WB, bB, afMid, nullptr, V);
    cheb_pass<2, 0><<<nb, 256, 0, stream>>>(X, Y, Y, Z, nullptr, slots, cursor, WB, nullptr, afMid, nullptr, V);
    if (blk < 2) {
      float* stI = stats + (3 + blk) * 8192;
      float* afI = affine + (3 + blk) * 32;
      cheb_pass<3, 2><<<nb, 256, 0, stream>>>(Y, X, nullptr, Z, C, slots, cursor, WB, nullptr, afIn, stI, V);
      bn_finalize<<<1, 16, 0, stream>>>(stI, gamma + (3 + blk) * 16, beta + (3 + blk) * 16, afI, invN);
    } else {
      cheb_pass<3, 3><<<nb, 256, 0, stream>>>(Y, X, nullptr, Z, C, slots, cursor, WB, nullptr, afIn, nullptr, V);
    }
    // rotate buffers
    half_t* oC = C; half_t* oY = Y; half_t* oZ = Z;
    C = oZ; Y = oC; Z = oY;
  }
  pool_kernel<<<256, 256, 0, stream>>>(C, part, V);
  pool_finish<<<1, 256, 0, stream>>>(part, (float*)d_out);
}